// Round 6
// baseline (189.948 us; speedup 1.0000x reference)
//
#include <hip/hip_runtime.h>

#define Bsz 8
#define Ssz 4096
#define Dsz 128

typedef short bf16x8 __attribute__((ext_vector_type(8)));
typedef float f32x4 __attribute__((ext_vector_type(4)));
typedef float f32x16 __attribute__((ext_vector_type(16)));
typedef int i32x2 __attribute__((ext_vector_type(2)));
typedef int i32x4 __attribute__((ext_vector_type(4)));
typedef unsigned int u32;

union B8 { u32 u[4]; bf16x8 v; };

// pack two fp32 -> bf16x2 (round half-up)
__device__ __forceinline__ u32 pkbf(float a, float b) {
  u32 ra = __float_as_uint(a) + 0x8000u;
  u32 rb = __float_as_uint(b) + 0x8000u;
  return __builtin_amdgcn_perm(rb, ra, 0x07060302u);  // lo16=bf(a), hi16=bf(b)
}

__device__ __forceinline__ void gll16(const void* g, void* l) {
  __builtin_amdgcn_global_load_lds((const __attribute__((address_space(1))) void*)g,
                                   (__attribute__((address_space(3))) void*)l, 16, 0, 0);
}

// Staged layouts (bf16), per 64-row tile (16KB):
//   Q/K: [gd 0..15][row s 0..63][8 d]   granule = 8 consecutive d at fixed s
//   V:   [gs 0..7][d 0..127][8 s]       granule = 8 consecutive s at fixed d

// ---------------- Projection ----------------
// grid 512 (64-row X tiles), 4 waves (wave w owns e-slice w*32). All operands in
// registers; LDS only for output tile assembly. W read strided from L2 (192KB hot).
__global__ __launch_bounds__(256, 2) void proj_kernel(
    const float* __restrict__ x, const float* __restrict__ wsrc,
    short* __restrict__ Qs, short* __restrict__ Ks, short* __restrict__ Vs) {
  __shared__ short ob[8192];  // 16KB output assembly

  const int rb = blockIdx.x;
  const int t = threadIdx.x;
  const int w = t >> 6, lane = t & 63, l31 = lane & 31, h = lane >> 5;

  // X frags: [st 2][c 8]: lane = s row (l31), k = d = c*16 + 8h + j
  bf16x8 xf[2][8];
  {
    const float* xs = x + (size_t)rb * 64 * Dsz;
    #pragma unroll
    for (int st = 0; st < 2; ++st)
      #pragma unroll
      for (int c = 0; c < 8; ++c) {
        const float* p = xs + (st * 32 + l31) * Dsz + c * 16 + 8 * h;
        f32x4 v0 = *(const f32x4*)p;
        f32x4 v1 = *(const f32x4*)(p + 4);
        B8 tmp;
        tmp.u[0] = pkbf(v0[0], v0[1]); tmp.u[1] = pkbf(v0[2], v0[3]);
        tmp.u[2] = pkbf(v1[0], v1[1]); tmp.u[3] = pkbf(v1[2], v1[3]);
        xf[st][c] = tmp.v;
      }
  }

  for (int mat = 0; mat < 3; ++mat) {
    const float* wm = wsrc + (size_t)mat * Dsz * Dsz;
    const float scale = (mat == 0) ? 1.44269504088896340736f : 1.0f;  // log2e in Wq
    // W frags: [c 8]: lane = e (w*32+l31), k = d = c*16+8h+j (strided row gather)
    bf16x8 wf[8];
    #pragma unroll
    for (int c = 0; c < 8; ++c) {
      const float* p = wm + (size_t)(c * 16 + 8 * h) * Dsz + w * 32 + l31;
      B8 tmp;
      #pragma unroll
      for (int j = 0; j < 4; ++j)
        tmp.u[j] = pkbf(p[(2 * j) * Dsz] * scale, p[(2 * j + 1) * Dsz] * scale);
      wf[c] = tmp.v;
    }

    if (mat < 2) {
      // C^T[e][s] = W(A, m=e) x X(B, n=s): col=lane&31=s, row=e=(r&3)+8(r>>2)+4h
      #pragma unroll
      for (int st = 0; st < 2; ++st) {
        f32x16 acc = {};
        #pragma unroll
        for (int c = 0; c < 8; ++c)
          acc = __builtin_amdgcn_mfma_f32_32x32x16_bf16(wf[c], xf[st][c], acc, 0, 0, 0);
        #pragma unroll
        for (int g = 0; g < 4; ++g) {
          int e0 = w * 32 + 8 * g + 4 * h;
          int s = st * 32 + l31;
          i32x2 pr;
          pr[0] = pkbf(acc[4 * g + 0], acc[4 * g + 1]);
          pr[1] = pkbf(acc[4 * g + 2], acc[4 * g + 3]);
          *(i32x2*)&ob[(e0 >> 3) * 512 + s * 8 + (e0 & 7)] = pr;  // [ge][s][8e]
        }
      }
    } else {
      // C[s][e] = X(A, m=s) x W(B, n=e): col=lane&31=e, row=s
      #pragma unroll
      for (int st = 0; st < 2; ++st) {
        f32x16 acc = {};
        #pragma unroll
        for (int c = 0; c < 8; ++c)
          acc = __builtin_amdgcn_mfma_f32_32x32x16_bf16(xf[st][c], wf[c], acc, 0, 0, 0);
        #pragma unroll
        for (int g = 0; g < 4; ++g) {
          int s0 = st * 32 + 8 * g + 4 * h;
          int e = w * 32 + l31;
          i32x2 pr;
          pr[0] = pkbf(acc[4 * g + 0], acc[4 * g + 1]);
          pr[1] = pkbf(acc[4 * g + 2], acc[4 * g + 3]);
          *(i32x2*)&ob[(s0 >> 3) * 1024 + e * 8 + (s0 & 7)] = pr;  // [gs][d][8s]
        }
      }
    }
    __syncthreads();
    short* dst = (mat == 0 ? Qs : mat == 1 ? Ks : Vs) + (size_t)rb * 8192;
    #pragma unroll
    for (int p = 0; p < 4; ++p)
      *(i32x4*)&dst[(p * 256 + t) * 8] = *(const i32x4*)&ob[(p * 256 + t) * 8];
    __syncthreads();
  }
}

// ---------------- Attention ----------------
// grid (8 b, 64 qt): q-tile 64, k-chunk 128/iter, 32 iters.
// 4 waves, k-split: wave w owns k-slice [w*32, w*32+32) of each chunk.
// P never touches LDS: S^T C-layout -> exp2 -> pack -> shfl_xor(32) -> PV A-frags.
__global__ __launch_bounds__(256, 2) void attn_kernel(
    const short* __restrict__ Qs, const short* __restrict__ Ks,
    const short* __restrict__ Vs, float* __restrict__ partial) {
  __shared__ short kbuf[16384];  // 32KB = 2 staged 64-row K tiles
  __shared__ short vbuf[16384];  // 32KB = 2 staged 64-row V tiles
  __shared__ float lsum[4][64];
  __shared__ float linv[64];
  __shared__ float pw[4][128];

  const int b = blockIdx.x;   // batch -> XCD (L2 locality)
  const int qt = blockIdx.y;
  const int t = threadIdx.x;
  const int w = t >> 6;
  const int lane = t & 63;
  const int l31 = lane & 31;
  const int h = lane >> 5;

  // Q B-frags: [nq 2][c 8], lane = q (l31), k = d = c*16+8h+j
  bf16x8 qf[2][8];
  {
    const short* qsrc = Qs + (size_t)(b * 64 + qt) * 8192;
    #pragma unroll
    for (int nq = 0; nq < 2; ++nq)
      #pragma unroll
      for (int c = 0; c < 8; ++c)
        qf[nq][c] = *(const bf16x8*)&qsrc[(2 * c + h) * 512 + (nq * 32 + l31) * 8];
  }

  f32x16 of[2][4];  // O[q 64][d 128] partial over this wave's k; col=lane&31=d, row=q
  #pragma unroll
  for (int nq = 0; nq < 2; ++nq)
    #pragma unroll
    for (int dt = 0; dt < 4; ++dt) of[nq][dt] = (f32x16){};
  float rs2[2] = {0.f, 0.f};

  const char* kb = (const char*)(Ks + (size_t)b * 64 * 8192);
  const char* vb = (const char*)(Vs + (size_t)b * 64 * 8192);
  const int kfbase = (w >> 1) * 8192 + ((w & 1) * 32 + l31) * 8;

  for (int it = 0; it < 32; ++it) {
    // ---- stage 128-k chunk: K 32KB + V 32KB, linear gll ----
    {
      const char* ks = kb + (size_t)it * 32768;
      const char* vs = vb + (size_t)it * 32768;
      #pragma unroll
      for (int i = 0; i < 8; ++i) {
        int p = w * 8 + i;
        gll16(ks + p * 1024 + lane * 16, (char*)kbuf + p * 1024);
        gll16(vs + p * 1024 + lane * 16, (char*)vbuf + p * 1024);
      }
    }
    __syncthreads();

    // ---- K A-frags for this wave's k-slice ----
    bf16x8 kf[8];
    #pragma unroll
    for (int c = 0; c < 8; ++c)
      kf[c] = *(const bf16x8*)&kbuf[kfbase + (2 * c + h) * 512];

    // ---- S^T = K·Q^T per q-half; exp2; pack; cross-half exchange -> P frags ----
    u32 pf[2][2][4];  // [nq][kc][4 u32] : A-layout P frags (lane=q, k=8h+j)
    #pragma unroll
    for (int nq = 0; nq < 2; ++nq) {
      f32x16 sc = {};
      #pragma unroll
      for (int c = 0; c < 8; ++c)
        sc = __builtin_amdgcn_mfma_f32_32x32x16_bf16(kf[c], qf[nq][c], sc, 0, 0, 0);
      float ps[16];
      float rsl = 0.f;
      #pragma unroll
      for (int r = 0; r < 16; ++r) {
        ps[r] = __builtin_amdgcn_exp2f(sc[r]);  // k = (r&3)+8*(r>>2)+4h, all same q
        rsl += ps[r];
      }
      rs2[nq] += rsl;
      u32 U[8];
      #pragma unroll
      for (int u = 0; u < 8; ++u) U[u] = pkbf(ps[2 * u], ps[2 * u + 1]);
      #pragma unroll
      for (int kc = 0; kc < 2; ++kc) {
        u32 sA = h ? U[4 * kc] : U[4 * kc + 2];
        u32 sB = h ? U[4 * kc + 1] : U[4 * kc + 3];
        u32 rA = (u32)__shfl_xor((int)sA, 32, 64);
        u32 rB = (u32)__shfl_xor((int)sB, 32, 64);
        pf[nq][kc][0] = h ? rA : U[4 * kc];
        pf[nq][kc][1] = h ? rB : U[4 * kc + 1];
        pf[nq][kc][2] = h ? U[4 * kc + 2] : rA;
        pf[nq][kc][3] = h ? U[4 * kc + 3] : rB;
      }
    }

    // ---- PV: O += P[64q x 32k] V[32k x 128d], registers only for P ----
    #pragma unroll
    for (int kc = 0; kc < 2; ++kc) {
      int sl = w * 32 + kc * 16 + 8 * h;  // slice-local s of this lane's V k-range
      int vbase = (sl >> 6) * 8192 + ((sl & 63) >> 3) * 1024;
      #pragma unroll
      for (int dt = 0; dt < 4; ++dt) {
        bf16x8 vf = *(const bf16x8*)&vbuf[vbase + (dt * 32 + l31) * 8];
        #pragma unroll
        for (int nq = 0; nq < 2; ++nq) {
          B8 pb;
          pb.u[0] = pf[nq][kc][0]; pb.u[1] = pf[nq][kc][1];
          pb.u[2] = pf[nq][kc][2]; pb.u[3] = pf[nq][kc][3];
          of[nq][dt] = __builtin_amdgcn_mfma_f32_32x32x16_bf16(pb.v, vf, of[nq][dt], 0, 0, 0);
        }
      }
    }
    __syncthreads();  // all reads done before restaging
  }

  // ---- softmax denominators (global over k: combine halves, then 4 waves) ----
  #pragma unroll
  for (int nq = 0; nq < 2; ++nq) {
    float v = rs2[nq] + __shfl_xor(rs2[nq], 32, 64);
    if (h == 0) lsum[w][nq * 32 + l31] = v;
  }
  __syncthreads();
  if (t < 64) {
    float l = lsum[0][t] + lsum[1][t] + lsum[2][t] + lsum[3][t];
    linv[t] = 1.f / (l * (float)Ssz);  // fold mean(1/S)
  }
  __syncthreads();

  // ---- weighted q-sum per d (normalization distributes over k-partials) ----
  float acc_d[4] = {0.f, 0.f, 0.f, 0.f};
  #pragma unroll
  for (int nq = 0; nq < 2; ++nq) {
    float li[16];
    #pragma unroll
    for (int r = 0; r < 16; ++r)
      li[r] = linv[nq * 32 + (r & 3) + 8 * (r >> 2) + 4 * h];
    #pragma unroll
    for (int dt = 0; dt < 4; ++dt) {
      float s = 0.f;
      #pragma unroll
      for (int r = 0; r < 16; ++r) s += of[nq][dt][r] * li[r];
      acc_d[dt] += s;
    }
  }
  #pragma unroll
  for (int dt = 0; dt < 4; ++dt) {
    acc_d[dt] += __shfl_xor(acc_d[dt], 32, 64);
    if (h == 0) pw[w][dt * 32 + l31] = acc_d[dt];
  }
  __syncthreads();
  if (t < 128) {
    float s = pw[0][t] + pw[1][t] + pw[2][t] + pw[3][t];
    partial[((size_t)b * 64 + qt) * 128 + t] = s;
  }
}

__global__ void reduce_kernel(const float* __restrict__ partial, float* __restrict__ out) {
  int i = blockIdx.x * 256 + threadIdx.x;
  if (i < Bsz * Dsz) {
    int b = i >> 7, d = i & 127;
    const float* p = partial + (size_t)b * 64 * 128 + d;
    float s = 0.f;
    #pragma unroll 8
    for (int q = 0; q < 64; ++q) s += p[q * 128];
    out[i] = s;
  }
}

extern "C" void kernel_launch(void* const* d_in, const int* in_sizes, int n_in,
                              void* d_out, int out_size, void* d_ws, size_t ws_size,
                              hipStream_t stream) {
  const float* x = (const float*)d_in[0];  // fp32 [8,4096,128]
  const float* w = (const float*)d_in[1];  // fp32 [3,128,128]
  short* Qs = (short*)d_ws;                               // 8MB bf16 staged
  short* Ks = Qs + (size_t)Bsz * Ssz * Dsz;               // 8MB
  short* Vs = Ks + (size_t)Bsz * Ssz * Dsz;               // 8MB
  float* partial = (float*)(Vs + (size_t)Bsz * Ssz * Dsz);  // 256KB

  proj_kernel<<<dim3(Bsz * Ssz / 64), dim3(256), 0, stream>>>(x, w, Qs, Ks, Vs);
  attn_kernel<<<dim3(Bsz, Ssz / 64), dim3(256), 0, stream>>>(Qs, Ks, Vs, partial);
  reduce_kernel<<<dim3(4), dim3(256), 0, stream>>>(partial, (float*)d_out);
}

// Round 7
// 156.566 us; speedup vs baseline: 1.2132x; 1.2132x over previous
//
#include <hip/hip_runtime.h>

#define Bsz 8
#define Ssz 4096
#define Dsz 128

typedef short bf16x8 __attribute__((ext_vector_type(8)));
typedef float f32x4 __attribute__((ext_vector_type(4)));
typedef float f32x16 __attribute__((ext_vector_type(16)));
typedef int i32x2 __attribute__((ext_vector_type(2)));
typedef int i32x4 __attribute__((ext_vector_type(4)));
typedef unsigned int u32;

union B8 { u32 u[4]; bf16x8 v; };

// pack two fp32 -> bf16x2 (round half-up)
__device__ __forceinline__ u32 pkbf(float a, float b) {
  u32 ra = __float_as_uint(a) + 0x8000u;
  u32 rb = __float_as_uint(b) + 0x8000u;
  return __builtin_amdgcn_perm(rb, ra, 0x07060302u);
}
__device__ __forceinline__ short f2bf(float f) {
  u32 r = __float_as_uint(f) + 0x8000u;
  return (short)(r >> 16);
}

__device__ __forceinline__ void gll16(const void* g, void* l) {
  __builtin_amdgcn_global_load_lds((const __attribute__((address_space(1))) void*)g,
                                   (__attribute__((address_space(3))) void*)l, 16, 0, 0);
}

// Staged Q/K layout (bf16), per 64-row tile (16KB): [gd 0..15][s 0..63][8 d]
// (granule = 8 consecutive d at fixed s). V is plain row-major [s][d].

// ---------------- Projection ----------------
// grid 512 (64-row X tiles), 4 waves (wave owns e-slice 32). Operands in registers
// (X strided-but-L1-resident, W coalesced); LDS only for output assembly.
__global__ __launch_bounds__(256, 2) void proj_kernel(
    const float* __restrict__ x, const float* __restrict__ wsrc,
    short* __restrict__ Qs, short* __restrict__ Ks, short* __restrict__ Vp) {
  __shared__ short ob[8192];  // 16KB output assembly

  const int rb = blockIdx.x;
  const int t = threadIdx.x;
  const int wv = t >> 6, lane = t & 63, l31 = lane & 31, h = lane >> 5;

  // X frags: [st 2][c 8]: lane = s row (l31), k = d = c*16 + 8h + j
  bf16x8 xf[2][8];
  {
    const float* xs = x + (size_t)rb * 64 * Dsz;
    #pragma unroll
    for (int st = 0; st < 2; ++st)
      #pragma unroll
      for (int c = 0; c < 8; ++c) {
        const float* p = xs + (st * 32 + l31) * Dsz + c * 16 + 8 * h;
        f32x4 v0 = *(const f32x4*)p;
        f32x4 v1 = *(const f32x4*)(p + 4);
        B8 tmp;
        tmp.u[0] = pkbf(v0[0], v0[1]); tmp.u[1] = pkbf(v0[2], v0[3]);
        tmp.u[2] = pkbf(v1[0], v1[1]); tmp.u[3] = pkbf(v1[2], v1[3]);
        xf[st][c] = tmp.v;
      }
  }

  for (int mat = 0; mat < 3; ++mat) {
    const float* wm = wsrc + (size_t)mat * Dsz * Dsz;
    const float scale = (mat == 0) ? 1.44269504088896340736f : 1.0f;  // log2e in Wq
    // W frags: lane = e (wv*32+l31), k = d = c*16+8h+j (coalesced 32-lane rows)
    bf16x8 wf[8];
    #pragma unroll
    for (int c = 0; c < 8; ++c) {
      const float* p = wm + (size_t)(c * 16 + 8 * h) * Dsz + wv * 32 + l31;
      B8 tmp;
      #pragma unroll
      for (int j = 0; j < 4; ++j)
        tmp.u[j] = pkbf(p[(2 * j) * Dsz] * scale, p[(2 * j + 1) * Dsz] * scale);
      wf[c] = tmp.v;
    }

    if (mat < 2) {
      // C^T[e][s] = W(A,m=e) x X(B,n=s): col=lane&31=s, row=e
      #pragma unroll
      for (int st = 0; st < 2; ++st) {
        f32x16 acc = {};
        #pragma unroll
        for (int c = 0; c < 8; ++c)
          acc = __builtin_amdgcn_mfma_f32_32x32x16_bf16(wf[c], xf[st][c], acc, 0, 0, 0);
        #pragma unroll
        for (int g = 0; g < 4; ++g) {
          int e0 = wv * 32 + 8 * g + 4 * h;
          int s = st * 32 + l31;
          i32x2 pr;
          pr[0] = pkbf(acc[4 * g + 0], acc[4 * g + 1]);
          pr[1] = pkbf(acc[4 * g + 2], acc[4 * g + 3]);
          *(i32x2*)&ob[(e0 >> 3) * 512 + s * 8 + (e0 & 7)] = pr;  // staged [ge][s][8e]
        }
      }
    } else {
      // C[s][e] = X(A,m=s) x W(B,n=e): col=lane&31=e, row=s -> row-major ob[s][e]
      #pragma unroll
      for (int st = 0; st < 2; ++st) {
        f32x16 acc = {};
        #pragma unroll
        for (int c = 0; c < 8; ++c)
          acc = __builtin_amdgcn_mfma_f32_32x32x16_bf16(xf[st][c], wf[c], acc, 0, 0, 0);
        int e = wv * 32 + l31;
        #pragma unroll
        for (int r = 0; r < 16; ++r) {
          int s = st * 32 + (r & 3) + 8 * (r >> 2) + 4 * h;
          ob[s * 128 + e] = f2bf(acc[r]);  // b16, 2 lanes/bank -> free
        }
      }
    }
    __syncthreads();
    short* dst = (mat == 0 ? Qs : mat == 1 ? Ks : Vp) + (size_t)rb * 8192;
    #pragma unroll
    for (int p = 0; p < 4; ++p)
      *(i32x4*)&dst[(p * 256 + t) * 8] = *(const i32x4*)&ob[(p * 256 + t) * 8];
    __syncthreads();
  }
}

// ---------------- Phase A: softmax denominators ----------------
// grid (8 b, 16 qt, 4 kt): q-tile 256 (wave owns 64 q), k-range 1024, chunks of 64.
// S^T = K·Q^T (col=lane=q) -> rowsum in-register. K double-buffered via gll16.
__global__ __launch_bounds__(256, 2) void lsum_kernel(
    const short* __restrict__ Qs, const short* __restrict__ Ks,
    float* __restrict__ lpart) {
  __shared__ short kbuf[2][8192];

  const int b = blockIdx.x, qt = blockIdx.y, kt = blockIdx.z;
  const int t = threadIdx.x;
  const int wv = t >> 6, lane = t & 63, l31 = lane & 31, h = lane >> 5;

  // Q B-frags: lane = q, k = d
  bf16x8 qf[2][8];
  {
    const short* qsrc = Qs + (size_t)(b * 64 + qt * 4 + wv) * 8192;
    #pragma unroll
    for (int nq = 0; nq < 2; ++nq)
      #pragma unroll
      for (int c = 0; c < 8; ++c)
        qf[nq][c] = *(const bf16x8*)&qsrc[(2 * c + h) * 512 + (nq * 32 + l31) * 8];
  }
  float rs2[2] = {0.f, 0.f};

  const char* kbase = (const char*)(Ks + (size_t)(b * 64 + kt * 16) * 8192);
  #define STAGE_K(it_, bf_)                                                     \
    { const char* src_ = kbase + (size_t)(it_) * 16384;                         \
      _Pragma("unroll")                                                         \
      for (int i_ = 0; i_ < 4; ++i_) {                                          \
        int p_ = wv * 4 + i_;                                                   \
        gll16(src_ + p_ * 1024 + lane * 16, (char*)kbuf[bf_] + p_ * 1024);      \
      } }

  STAGE_K(0, 0);
  __syncthreads();

  for (int it = 0; it < 16; ++it) {
    const int cur = it & 1;
    if (it < 15) STAGE_K(it + 1, cur ^ 1);
    #pragma unroll
    for (int mk = 0; mk < 2; ++mk) {
      bf16x8 kf[8];  // A-frags: lane = k-row
      #pragma unroll
      for (int c = 0; c < 8; ++c)
        kf[c] = *(const bf16x8*)&kbuf[cur][(2 * c + h) * 512 + (mk * 32 + l31) * 8];
      f32x16 s0 = {}, s1 = {};
      #pragma unroll
      for (int c = 0; c < 8; ++c) {
        s0 = __builtin_amdgcn_mfma_f32_32x32x16_bf16(kf[c], qf[0][c], s0, 0, 0, 0);
        s1 = __builtin_amdgcn_mfma_f32_32x32x16_bf16(kf[c], qf[1][c], s1, 0, 0, 0);
      }
      #pragma unroll
      for (int r = 0; r < 16; ++r) rs2[0] += __builtin_amdgcn_exp2f(s0[r]);
      #pragma unroll
      for (int r = 0; r < 16; ++r) rs2[1] += __builtin_amdgcn_exp2f(s1[r]);
    }
    __syncthreads();
  }

  #pragma unroll
  for (int nq = 0; nq < 2; ++nq) {
    float v = rs2[nq] + __shfl_xor(rs2[nq], 32, 64);
    if (h == 0)
      lpart[((size_t)kt * 8 + b) * 4096 + qt * 256 + wv * 64 + nq * 32 + l31] = v;
  }
}

// ---------------- Phase B: g[k] = sum_q linv[q] exp(S) ; out += g·V ----------------
// Same grid/tiling. S = Q·K^T (col=lane=k) -> linv-weighted q-reduction in-register.
__global__ __launch_bounds__(256, 2) void attnv_kernel(
    const short* __restrict__ Qs, const short* __restrict__ Ks,
    const short* __restrict__ Vp, const float* __restrict__ lpart,
    float* __restrict__ partials) {
  __shared__ short kbuf[2][8192];
  __shared__ float linv_lds[256];
  __shared__ float gw[4][1024];
  __shared__ float pwb[512];

  const int b = blockIdx.x, qt = blockIdx.y, kt = blockIdx.z;
  const int t = threadIdx.x;
  const int wv = t >> 6, lane = t & 63, l31 = lane & 31, h = lane >> 5;

  {  // denominators for this block's 256 q
    int q = qt * 256 + t;
    float l = lpart[(size_t)b * 4096 + q] + lpart[((size_t)1 * 8 + b) * 4096 + q] +
              lpart[((size_t)2 * 8 + b) * 4096 + q] + lpart[((size_t)3 * 8 + b) * 4096 + q];
    linv_lds[t] = 1.f / (l * (float)Ssz);  // fold mean over S
  }

  bf16x8 qf[2][8];  // A-frags: lane = q-row
  {
    const short* qsrc = Qs + (size_t)(b * 64 + qt * 4 + wv) * 8192;
    #pragma unroll
    for (int mq = 0; mq < 2; ++mq)
      #pragma unroll
      for (int c = 0; c < 8; ++c)
        qf[mq][c] = *(const bf16x8*)&qsrc[(2 * c + h) * 512 + (mq * 32 + l31) * 8];
  }
  __syncthreads();  // linv ready

  float li[2][16];
  #pragma unroll
  for (int mq = 0; mq < 2; ++mq)
    #pragma unroll
    for (int r = 0; r < 16; ++r)
      li[mq][r] = linv_lds[wv * 64 + mq * 32 + (r & 3) + 8 * (r >> 2) + 4 * h];

  const char* kbase = (const char*)(Ks + (size_t)(b * 64 + kt * 16) * 8192);
  STAGE_K(0, 0);
  __syncthreads();

  for (int it = 0; it < 16; ++it) {
    const int cur = it & 1;
    if (it < 15) STAGE_K(it + 1, cur ^ 1);
    #pragma unroll
    for (int nk = 0; nk < 2; ++nk) {
      bf16x8 kf[8];  // B-frags: lane = k
      #pragma unroll
      for (int c = 0; c < 8; ++c)
        kf[c] = *(const bf16x8*)&kbuf[cur][(2 * c + h) * 512 + (nk * 32 + l31) * 8];
      f32x16 s0 = {}, s1 = {};
      #pragma unroll
      for (int c = 0; c < 8; ++c) {
        s0 = __builtin_amdgcn_mfma_f32_32x32x16_bf16(qf[0][c], kf[c], s0, 0, 0, 0);
        s1 = __builtin_amdgcn_mfma_f32_32x32x16_bf16(qf[1][c], kf[c], s1, 0, 0, 0);
      }
      float gp = 0.f;
      #pragma unroll
      for (int r = 0; r < 16; ++r)
        gp += li[0][r] * __builtin_amdgcn_exp2f(s0[r]) +
              li[1][r] * __builtin_amdgcn_exp2f(s1[r]);
      gp += __shfl_xor(gp, 32, 64);
      if (h == 0) gw[wv][it * 64 + nk * 32 + l31] = gp;
    }
    __syncthreads();
  }

  // combine 4 waves' g partials
  #pragma unroll
  for (int j = 0; j < 4; ++j) {
    int idx = j * 256 + t;
    gw[0][idx] = gw[0][idx] + gw[1][idx] + gw[2][idx] + gw[3][idx];
  }
  __syncthreads();

  // V sweep: thread handles d-pair (2dp, 2dp+1), k-quarter kq (256 k)
  {
    const int dp = t & 63, kq = t >> 6;
    const short* vr = Vp + ((size_t)b * 4096 + kt * 1024 + kq * 256) * 128 + 2 * dp;
    float a0 = 0.f, a1 = 0.f;
    #pragma unroll 8
    for (int k = 0; k < 256; ++k) {
      u32 pair = *(const u32*)&vr[(size_t)k * 128];
      float g = gw[0][kq * 256 + k];
      a0 += g * __uint_as_float(pair << 16);
      a1 += g * __uint_as_float(pair & 0xffff0000u);
    }
    pwb[kq * 128 + 2 * dp] = a0;
    pwb[kq * 128 + 2 * dp + 1] = a1;
  }
  __syncthreads();
  if (t < 128) {
    float s = pwb[t] + pwb[128 + t] + pwb[256 + t] + pwb[384 + t];
    partials[((size_t)(qt * 4 + kt) * 8 + b) * 128 + t] = s;
  }
}

__global__ void finalize_kernel(const float* __restrict__ partials, float* __restrict__ out) {
  int i = blockIdx.x * 256 + threadIdx.x;
  if (i < Bsz * Dsz) {
    int b = i >> 7, d = i & 127;
    float s = 0.f;
    #pragma unroll 8
    for (int j = 0; j < 64; ++j) s += partials[((size_t)j * 8 + b) * 128 + d];
    out[i] = s;
  }
}

extern "C" void kernel_launch(void* const* d_in, const int* in_sizes, int n_in,
                              void* d_out, int out_size, void* d_ws, size_t ws_size,
                              hipStream_t stream) {
  const float* x = (const float*)d_in[0];  // fp32 [8,4096,128]
  const float* w = (const float*)d_in[1];  // fp32 [3,128,128]
  short* Qs = (short*)d_ws;                                // 8MB bf16 staged
  short* Ks = Qs + (size_t)Bsz * Ssz * Dsz;                // 8MB staged
  short* Vp = Ks + (size_t)Bsz * Ssz * Dsz;                // 8MB row-major
  float* lpart = (float*)(Vp + (size_t)Bsz * Ssz * Dsz);   // 512KB [kt4][b8][q4096]
  float* partials = lpart + 4 * Bsz * Ssz;                 // 256KB [qkt64][b8][d128]

  proj_kernel<<<dim3(Bsz * Ssz / 64), dim3(256), 0, stream>>>(x, w, Qs, Ks, Vp);
  lsum_kernel<<<dim3(Bsz, 16, 4), dim3(256), 0, stream>>>(Qs, Ks, lpart);
  attnv_kernel<<<dim3(Bsz, 16, 4), dim3(256), 0, stream>>>(Qs, Ks, Vp, lpart, partials);
  finalize_kernel<<<dim3(4), dim3(256), 0, stream>>>(partials, (float*)d_out);
}